// Round 9
// baseline (1141.075 us; speedup 1.0000x reference)
//
#include <hip/hip_runtime.h>
#include <hip/hip_bf16.h>

#define EPSV 1e-5f
#define SPSHIFT 9           // super-partition = 512 nodes
#define SPMASK 511
#define NBINS 256           // k_binsort grid (one block per CU, exact edge split)
#define CAPS 10240          // k_build2 LDS sort capacity (mean 8192, +22 sigma)

typedef __attribute__((ext_vector_type(8))) short bf16x8;
typedef __attribute__((ext_vector_type(4))) float f32x4;

__device__ __forceinline__ float bf2f(unsigned short u) {
    unsigned x = ((unsigned)u) << 16;
    return __builtin_bit_cast(float, x);
}
__device__ __forceinline__ unsigned short f2bf(float f) {
    unsigned x = __builtin_bit_cast(unsigned, f);
    unsigned r = (x + 0x7fffu + ((x >> 16) & 1u)) >> 16;  // RNE
    return (unsigned short)r;
}

// ---------------- CSR build: block-local counting sort ----------------
// R8 lesson: per-edge dword scatter into device-wide buckets costs exactly
// 32 B/edge of writeback (51 MB) no matter the bucket capacity -- lines fill
// too slowly, from multiple XCDs. Fix: each block sorts its OWN 6250-edge
// slice by super-partition in LDS and writes a private contiguous 25 KB
// segment (hot window, one CU) -> full-line writebacks, ~6.4 MB total.

// block b: edges [b*chunk, b*chunk+chunk). pass1 hist by dst>>9, LDS scan,
// pass2 scatter payload=(src<<9 | dst&511) into staging[b*chunk + pos].
__global__ __launch_bounds__(256) void k_binsort(const int* __restrict__ src,
                                                 const int* __restrict__ dst,
                                                 unsigned* __restrict__ staging,
                                                 int* __restrict__ bh,
                                                 int E, int chunk, int NSP) {
    __shared__ int cnt[256], red[256];
    int b = blockIdx.x, t = threadIdx.x;
    int lo = b * chunk, hi = min(lo + chunk, E);
    cnt[t] = 0;
    __syncthreads();
    for (int i = lo + t; i < hi; i += 256) atomicAdd(&cnt[dst[i] >> SPSHIFT], 1);
    __syncthreads();
    int v = cnt[t];
    red[t] = v;
    __syncthreads();
    for (int d = 1; d < 256; d <<= 1) {
        int u = (t >= d) ? red[t - d] : 0;
        __syncthreads();
        red[t] += u;
        __syncthreads();
    }
    if (t < NSP) bh[b * NSP + t] = v;   // per-(block,SP) count
    cnt[t] = red[t] - v;                // exclusive prefix -> cursor
    __syncthreads();
    for (int i = lo + t; i < hi; i += 256) {
        int d = dst[i], s = src[i];
        int pos = atomicAdd(&cnt[d >> SPSHIFT], 1);
        staging[(size_t)lo + pos] = ((unsigned)s << SPSHIFT) | (unsigned)(d & SPMASK);
    }
}

// block 0: per-SP cross-block prefix (start[b][sp]) + SP base scan + off[N]=E
// block 1: graph bounds from sorted batch
__global__ __launch_bounds__(256) void k_meta2(const int* __restrict__ bh,
                                               int* __restrict__ start,
                                               int* __restrict__ spbase,
                                               int* __restrict__ off,
                                               const int* __restrict__ batch,
                                               int* __restrict__ gstart,
                                               int NSP, int Nn, int G, int E) {
    if (blockIdx.x == 1) {
        int g = threadIdx.x;
        if (g > G) return;
        if (g == G) {
            gstart[G] = Nn;
            return;
        }
        int lo = 0, hi = Nn;
        while (lo < hi) {
            int mid = (lo + hi) >> 1;
            if (batch[mid] < g) lo = mid + 1;
            else hi = mid;
        }
        gstart[g] = lo;
        return;
    }
    __shared__ int red[256];
    int t = threadIdx.x;  // = sp
    int s = 0;
    if (t < NSP) {
        for (int b = 0; b < NBINS; b++) {
            start[b * NSP + t] = s;
            s += bh[b * NSP + t];
        }
    }
    red[t] = (t < NSP) ? s : 0;
    __syncthreads();
    for (int d = 1; d < 256; d <<= 1) {
        int u = (t >= d) ? red[t - d] : 0;
        __syncthreads();
        red[t] += u;
        __syncthreads();
    }
    if (t < NSP) spbase[t] = red[t] - s;  // exclusive
    if (t == 255) off[Nn] = E;
}

// one block per SP: pass1 degree histogram (512 bins) from the 256 runs,
// scan -> coalesced off[] write; pass2 scatter into LDS srt; coalesced csr.
__global__ __launch_bounds__(256) void k_build2(const unsigned* __restrict__ staging,
                                                const int* __restrict__ bh,
                                                const int* __restrict__ start,
                                                const int* __restrict__ spbase,
                                                int* __restrict__ off,
                                                int* __restrict__ csr,
                                                int chunk, int NSP, int Nn) {
    __shared__ int cnt[512], loff[512], cur[512], red[256];
    __shared__ unsigned srt[CAPS];
    int sp = blockIdx.x, t = threadIdx.x;
    int wave = t >> 6, lane = t & 63;
    cnt[t] = 0;
    cnt[t + 256] = 0;
    __syncthreads();
    for (int b = wave; b < NBINS; b += 4) {
        int st = start[b * NSP + sp], c = bh[b * NSP + sp];
        const unsigned* rp = staging + (size_t)b * chunk + st;
        for (int j = lane; j < c; j += 64) atomicAdd(&cnt[rp[j] & SPMASK], 1);
    }
    __syncthreads();
    int a0 = cnt[2 * t], a1 = cnt[2 * t + 1];
    int v = a0 + a1;
    red[t] = v;
    __syncthreads();
    for (int d = 1; d < 256; d <<= 1) {
        int u = (t >= d) ? red[t - d] : 0;
        __syncthreads();
        red[t] += u;
        __syncthreads();
    }
    int ex = red[t] - v;
    loff[2 * t] = ex;
    loff[2 * t + 1] = ex + a0;
    __syncthreads();
    int tot = min(red[255], CAPS);
    int base = spbase[sp];
    int node0 = sp << SPSHIFT;
    if (node0 + t < Nn) off[node0 + t] = base + loff[t];
    if (node0 + 256 + t < Nn) off[node0 + 256 + t] = base + loff[256 + t];
    cur[2 * t] = loff[2 * t];
    cur[2 * t + 1] = loff[2 * t + 1];
    __syncthreads();
    for (int b = wave; b < NBINS; b += 4) {
        int st = start[b * NSP + sp], c = bh[b * NSP + sp];
        const unsigned* rp = staging + (size_t)b * chunk + st;
        for (int j = lane; j < c; j += 64) {
            unsigned e = rp[j];
            int pos = atomicAdd(&cur[e & SPMASK], 1);
            if (pos < CAPS) srt[pos] = e >> SPSHIFT;
        }
    }
    __syncthreads();
    for (int j = t; j < tot; j += 256) csr[base + j] = (int)srt[j];
}

// ---------------- aggregation ----------------

__global__ __launch_bounds__(256) void k_agg7(const float* __restrict__ x,
                                              const int* __restrict__ off,
                                              const int* __restrict__ csr,
                                              float* __restrict__ mean, int n) {
    int i = (blockIdx.x * 256 + threadIdx.x) >> 3;
    int r = threadIdx.x & 7;
    if (i >= n) return;
    int a = off[i], b = off[i + 1];
    float acc = 0.f;
    if (r < 7) {
        int j = a;
        for (; j + 1 < b; j += 2)
            acc += x[(size_t)csr[j] * 7 + r] + x[(size_t)csr[j + 1] * 7 + r];
        if (j < b) acc += x[(size_t)csr[j] * 7 + r];
    }
    float inv = 1.0f / (float)max(b - a, 1);
    if (r < 7) mean[(size_t)i * 7 + r] = acc * inv;
}

__global__ __launch_bounds__(256) void k_agg128(const unsigned short* __restrict__ x,
                                                const int* __restrict__ off,
                                                const int* __restrict__ csr,
                                                unsigned short* __restrict__ mean,
                                                int n) {
    int h = (blockIdx.x * 256 + threadIdx.x) >> 5;  // half-wave = node
    int sl = threadIdx.x & 31;
    if (h >= n) return;
    int a = off[h], b = off[h + 1];
    float a0 = 0.f, a1 = 0.f, a2 = 0.f, a3 = 0.f;
    int j = a;
    for (; j + 3 < b; j += 4) {
        int s0 = csr[j], s1 = csr[j + 1], s2 = csr[j + 2], s3 = csr[j + 3];
        ushort4 v0 = *(const ushort4*)&x[(size_t)s0 * 128 + sl * 4];
        ushort4 v1 = *(const ushort4*)&x[(size_t)s1 * 128 + sl * 4];
        ushort4 v2 = *(const ushort4*)&x[(size_t)s2 * 128 + sl * 4];
        ushort4 v3 = *(const ushort4*)&x[(size_t)s3 * 128 + sl * 4];
        a0 += bf2f(v0.x) + bf2f(v1.x) + bf2f(v2.x) + bf2f(v3.x);
        a1 += bf2f(v0.y) + bf2f(v1.y) + bf2f(v2.y) + bf2f(v3.y);
        a2 += bf2f(v0.z) + bf2f(v1.z) + bf2f(v2.z) + bf2f(v3.z);
        a3 += bf2f(v0.w) + bf2f(v1.w) + bf2f(v2.w) + bf2f(v3.w);
    }
    for (; j < b; j++) {
        ushort4 v = *(const ushort4*)&x[(size_t)csr[j] * 128 + sl * 4];
        a0 += bf2f(v.x);
        a1 += bf2f(v.y);
        a2 += bf2f(v.z);
        a3 += bf2f(v.w);
    }
    float inv = 1.0f / (float)max(b - a, 1);
    ushort4 o;
    o.x = f2bf(a0 * inv);
    o.y = f2bf(a1 * inv);
    o.z = f2bf(a2 * inv);
    o.w = f2bf(a3 * inv);
    *(ushort4*)&mean[(size_t)h * 128 + sl * 4] = o;
}

// ---------------- weight prep: all 4 matrices in one launch ----------------

__global__ __launch_bounds__(256) void k_prepw_all(
    const float* __restrict__ Wl1, const float* __restrict__ Wr1,
    const float* __restrict__ Wl2, const float* __restrict__ Wr2,
    unsigned short* __restrict__ Wlt1, unsigned short* __restrict__ Wrt1,
    unsigned short* __restrict__ Wlt2, unsigned short* __restrict__ Wrt2) {
    int u = blockIdx.x * 256 + threadIdx.x;
    const float* W;
    unsigned short* Wt;
    int Ncols, v;
    if (u < 32768) {
        v = u & 16383;
        W = (u < 16384) ? Wl1 : Wr1;
        Wt = (u < 16384) ? Wlt1 : Wrt1;
        Ncols = 128;
    } else {
        v = (u - 32768) & 32767;
        W = (u < 65536) ? Wl2 : Wr2;
        Wt = (u < 65536) ? Wlt2 : Wrt2;
        Ncols = 256;
    }
    int n = v % Ncols, k = v / Ncols;
    Wt[(size_t)n * 128 + k] = f2bf(W[(size_t)k * Ncols + n]);
}

// ---------------- layer 0 (din=7, fp32 vector) -> bf16 out ----------------

__global__ __launch_bounds__(256) void k_layer0(
    const float* __restrict__ x, const float* __restrict__ mean,
    const float* __restrict__ Wl, const float* __restrict__ bl,
    const float* __restrict__ Wr, const float* __restrict__ g,
    const float* __restrict__ be, const float* __restrict__ rm,
    const float* __restrict__ rv, unsigned short* __restrict__ out, int n) {
    int tid = threadIdx.x;
    int col = tid & 127;
    int r = tid >> 7;
    int row = blockIdx.x * 2 + r;
    if (row >= n) return;
    float sc = g[col] * rsqrtf(rv[col] + EPSV);
    float sh = (bl[col] - rm[col]) * sc + be[col];
    const float* xp = x + (size_t)row * 7;
    const float* mp = mean + (size_t)row * 7;
    float acc = 0.f;
#pragma unroll
    for (int k = 0; k < 7; k++) acc += xp[k] * Wl[k * 128 + col];
#pragma unroll
    for (int k = 0; k < 7; k++) acc += mp[k] * Wr[k * 128 + col];
    float h = acc * sc + sh;
    out[(size_t)row * 128 + col] = f2bf(fmaxf(h, 0.f));
}

// ---------------- MFMA layer (K = 2x128, bf16 inputs, fp32 accum) ----------------
// 64 rows x COLS(=128) per block, 16 rows/wave, acc = 8 x f32x4 = 32 VGPRs,
// LDS 15 KB -> ~6 blocks/CU. Layer 1: COLS=DOUT=128, grid.y=1 (in-place safe).
// Layer 2: COLS=128, grid.y=2 (x3 output disjoint from inputs).

template <int COLS, int DOUT, bool BF16OUT>
__global__ __launch_bounds__(256) void k_mfma_layer(
    const unsigned short* __restrict__ xin, const unsigned short* __restrict__ meanb,
    const unsigned short* __restrict__ Wlt, const unsigned short* __restrict__ Wrt,
    const float* __restrict__ bl, const float* __restrict__ g,
    const float* __restrict__ be, const float* __restrict__ rm,
    const float* __restrict__ rv, void* __restrict__ outv, int n) {
    __shared__ unsigned short As[64 * 40];
    __shared__ unsigned short Bs[COLS * 40];

    int tid = threadIdx.x;
    int wave = tid >> 6;
    int lane = tid & 63;
    int m = lane & 15;
    int half = lane >> 4;
    int row0 = blockIdx.x * 64;
    int colbase = blockIdx.y * COLS;

    const int NCB = COLS / 16;
    f32x4 acc[NCB] = {};

    for (int s = 0; s < 8; s++) {
        int pass = s >> 2;
        int k0 = (s & 3) * 32;
        const unsigned short* Asrc = pass ? meanb : xin;
        const unsigned short* Wt = pass ? Wrt : Wlt;

        __syncthreads();
        {   // stage A: 64 rows x 32 k
            int rr = tid >> 2;
            int ks = (tid & 3) * 8;
            int grow = row0 + rr;
            float4 v = make_float4(0.f, 0.f, 0.f, 0.f);
            if (grow < n) v = *(const float4*)&Asrc[(size_t)grow * 128 + k0 + ks];
            *(float4*)&As[rr * 40 + ks] = v;
        }
#pragma unroll
        for (int rep = 0; rep < COLS / 64; rep++) {  // stage B: COLS cols x 32 k
            int u = tid + rep * 256;
            int nn = u >> 2;
            int ks = (u & 3) * 8;
            float4 v = *(const float4*)&Wt[(size_t)(colbase + nn) * 128 + k0 + ks];
            *(float4*)&Bs[nn * 40 + ks] = v;
        }
        __syncthreads();

        bf16x8 a = *(const bf16x8*)&As[(wave * 16 + m) * 40 + half * 8];
#pragma unroll
        for (int cb = 0; cb < NCB; cb++) {
            bf16x8 b = *(const bf16x8*)&Bs[(cb * 16 + m) * 40 + half * 8];
            acc[cb] = __builtin_amdgcn_mfma_f32_16x16x32_bf16(a, b, acc[cb], 0, 0, 0);
        }
    }

    float* outf = (float*)outv;
    unsigned short* outb = (unsigned short*)outv;
#pragma unroll
    for (int cb = 0; cb < NCB; cb++) {
        int col = colbase + cb * 16 + m;
        float sc = g[col] * rsqrtf(rv[col] + EPSV);
        float sh = (bl[col] - rm[col]) * sc + be[col];
#pragma unroll
        for (int reg = 0; reg < 4; reg++) {
            int r0 = row0 + wave * 16 + half * 4 + reg;
            if (r0 < n) {
                float h = fmaxf(acc[cb][reg] * sc + sh, 0.f);
                if (BF16OUT) outb[(size_t)r0 * DOUT + col] = f2bf(h);
                else outf[(size_t)r0 * DOUT + col] = h;
            }
        }
    }
}

// ---------------- pooling ----------------

__global__ __launch_bounds__(256) void k_pool(const float* __restrict__ x3,
                                              const int* __restrict__ gstart,
                                              float* __restrict__ pooled, int G) {
    const int S = 16;
    int g = blockIdx.x / S;
    int s = blockIdx.x % S;
    int a = gstart[g], b = gstart[g + 1];
    int col = threadIdx.x;
    float acc = 0.f;
    for (int r = a + s; r < b; r += S) acc += x3[(size_t)r * 256 + col];
    atomicAdd(&pooled[g * 256 + col], acc);
}

// ---------------- launch ----------------

extern "C" void kernel_launch(void* const* d_in, const int* in_sizes, int n_in,
                              void* d_out, int out_size, void* d_ws, size_t ws_size,
                              hipStream_t stream) {
    const float* x = (const float*)d_in[0];
    const int* ei = (const int*)d_in[1];
    const int* batch = (const int*)d_in[2];
    const int N = in_sizes[0] / 7;
    const int E = in_sizes[1] / 2;
    const int G = 64;
    const int* src = ei;
    const int* dst = ei + E;
    const int NSP = (N + SPMASK) >> SPSHIFT;   // 196 for N=100000
    const int chunk = (E + NBINS - 1) / NBINS; // 6250 for E=1.6M

    const float* P[21];
    for (int i = 0; i < 21; i++) P[i] = (const float*)d_in[3 + i];
    const float **L0 = P, **L1 = P + 7, **L2 = P + 14;

    char* w = (char*)d_ws;
    auto carve = [&](size_t bytes) {
        void* p = (void*)w;
        w += (bytes + 255) & ~(size_t)255;
        return p;
    };
    unsigned* staging = (unsigned*)carve((size_t)NBINS * chunk * 4);
    int* bh = (int*)carve((size_t)NBINS * NSP * 4);
    int* start = (int*)carve((size_t)NBINS * NSP * 4);
    int* spbase = (int*)carve((size_t)NSP * 4);
    int* off = (int*)carve(((size_t)N + 1) * 4);
    int* csr = (int*)carve((size_t)E * 4);
    int* gstart = (int*)carve(((size_t)G + 1) * 4);
    float* mean7 = (float*)carve((size_t)N * 7 * 4);
    unsigned short* x1 = (unsigned short*)carve((size_t)N * 128 * 2);
    unsigned short* meanb = (unsigned short*)carve((size_t)N * 128 * 2);
    unsigned short* Wlt1 = (unsigned short*)carve((size_t)128 * 128 * 2);
    unsigned short* Wrt1 = (unsigned short*)carve((size_t)128 * 128 * 2);
    unsigned short* Wlt2 = (unsigned short*)carve((size_t)128 * 256 * 2);
    unsigned short* Wrt2 = (unsigned short*)carve((size_t)128 * 256 * 2);

    float* pooled = (float*)d_out;
    float* x3 = (float*)d_out + (size_t)G * 256;

    hipMemsetAsync(pooled, 0, (size_t)G * 256 * 4, stream);

    // CSR build: block-local counting sort (no device-wide scatter)
    k_binsort<<<NBINS, 256, 0, stream>>>(src, dst, staging, bh, E, chunk, NSP);
    k_meta2<<<2, 256, 0, stream>>>(bh, start, spbase, off, batch, gstart, NSP, N, G, E);
    k_build2<<<NSP, 256, 0, stream>>>(staging, bh, start, spbase, off, csr, chunk, NSP, N);
    k_prepw_all<<<(98304 + 255) / 256, 256, 0, stream>>>(L1[0], L1[2], L2[0], L2[2],
                                                         Wlt1, Wrt1, Wlt2, Wrt2);

    // layer 0: din=7 -> 128 (fp32 vector, bf16 out)
    k_agg7<<<(N * 8 + 255) / 256, 256, 0, stream>>>(x, off, csr, mean7, N);
    k_layer0<<<(N + 1) / 2, 256, 0, stream>>>(x, mean7, L0[0], L0[1], L0[2], L0[3],
                                              L0[4], L0[5], L0[6], x1, N);

    // layer 1: 128 -> 128, MFMA, in-place on x1 (full-width blocks own their rows)
    k_agg128<<<(N + 7) / 8, 256, 0, stream>>>(x1, off, csr, meanb, N);
    k_mfma_layer<128, 128, true><<<dim3((N + 63) / 64, 1), 256, 0, stream>>>(
        x1, meanb, Wlt1, Wrt1, L1[1], L1[3], L1[4], L1[5], L1[6], x1, N);

    // layer 2: 128 -> 256, MFMA, fp32 out into d_out x-region
    k_agg128<<<(N + 7) / 8, 256, 0, stream>>>(x1, off, csr, meanb, N);
    k_mfma_layer<128, 256, false><<<dim3((N + 63) / 64, 2), 256, 0, stream>>>(
        x1, meanb, Wlt2, Wrt2, L2[1], L2[3], L2[4], L2[5], L2[6], x3, N);

    // global add pool
    k_pool<<<G * 16, 256, 0, stream>>>(x3, gstart, pooled, G);
}